// Round 10
// baseline (336.287 us; speedup 1.0000x reference)
//
#include <hip/hip_runtime.h>
#include <hip/hip_fp16.h>

// 3-layer GCN (PyG GCNConv semantics): deg/norm build -> CSR by dst ->
// per layer: fp16 MFMA GEMM (fp32 accum) then CSR aggregation (fp16 gather,
// fp32 accumulate) + bias (+relu), final 128->16 linear fused into last agg.
//
// R10: (1) GEMM C-epilogue through LDS (was 8.2M scattered 2-B stores);
// x->fp16 folded into GEMM1's staging (k_convx dropped); convW x3 merged;
// k_dis folded into k_scanA. (2) k_probe<1>: full-grid agg clone with
// laundered self-index gather (same instruction structure, zero randomness)
// -> discriminates random-access-service vs structural agg bottleneck via
// its presence/absence in top-5.

#define FD 128
#define NCLS 16

typedef _Float16 f16x8 __attribute__((ext_vector_type(8)));
typedef float f32x4 __attribute__((ext_vector_type(4)));

__global__ __launch_bounds__(256) void k_init_deg(int* __restrict__ degi, int n) {
  int i = blockIdx.x * 256 + threadIdx.x;
  if (i < n) degi[i] = 1;  // self-loop
}

__global__ __launch_bounds__(256) void k_count(const int* __restrict__ dst,
                                               int* __restrict__ degi, int e) {
  int i = blockIdx.x * 256 + threadIdx.x;
  if (i < e) atomicAdd(&degi[dst[i]], 1);
}

// Phase A: per-1024-chunk exclusive scan of (deg-1); also emits dis=rsqrt(deg)
__global__ __launch_bounds__(1024) void k_scanA(const int* __restrict__ degi,
                                                int* __restrict__ ptr,
                                                int* __restrict__ bsum,
                                                float* __restrict__ dis, int n) {
  __shared__ int buf[1024];
  int tid = threadIdx.x;
  int i = blockIdx.x * 1024 + tid;
  int dg = (i < n) ? degi[i] : 1;
  if (i < n) dis[i] = rsqrtf((float)dg);
  int v = (i < n) ? (dg - 1) : 0;
  buf[tid] = v;
  __syncthreads();
  for (int off = 1; off < 1024; off <<= 1) {
    int t = (tid >= off) ? buf[tid - off] : 0;
    __syncthreads();
    buf[tid] += t;
    __syncthreads();
  }
  if (i < n) ptr[i] = buf[tid] - v;  // local exclusive
  if (tid == 1023) bsum[blockIdx.x] = buf[1023];
}

// Phase B: tiny serial scan of ~49 block sums
__global__ void k_scanB(int* __restrict__ bsum, int nb) {
  if (threadIdx.x == 0 && blockIdx.x == 0) {
    int run = 0;
    for (int b = 0; b < nb; ++b) { int t = bsum[b]; bsum[b] = run; run += t; }
  }
}

// Phase C: add chunk offsets, init fill cursors, write ptr[n]
__global__ __launch_bounds__(256) void k_scanC(int* __restrict__ ptr,
                                               int* __restrict__ cur,
                                               const int* __restrict__ bsum,
                                               int n, int e) {
  int i = blockIdx.x * 256 + threadIdx.x;
  if (i < n) {
    int p = ptr[i] + bsum[i >> 10];
    ptr[i] = p;
    cur[i] = p;
  }
  if (i == 0) ptr[n] = e;
}

__global__ __launch_bounds__(256) void k_fill(const int* __restrict__ src,
                                              const int* __restrict__ dst,
                                              int* __restrict__ cur,
                                              const float* __restrict__ dis,
                                              int2* __restrict__ sn, int e) {
  int i = blockIdx.x * 256 + threadIdx.x;
  if (i < e) {
    int s = src[i], d = dst[i];
    int p = atomicAdd(&cur[d], 1);
    sn[p] = make_int2(s, __float_as_int(dis[s] * dis[d]));
  }
}

// Pack W1,W2,W3 (each 128x128 fp32 row-major) into per-lane B-fragment order:
// wp[((c*4+kc)*64 + l)*8 + j] = W[kc*32 + (l>>4)*8 + j][c*16 + (l&15)].
// grid = 192 blocks x 256 = 3 x 16384.
__global__ __launch_bounds__(256) void k_convW3(const float* __restrict__ W1,
                                                const float* __restrict__ W2,
                                                const float* __restrict__ W3,
                                                __half* __restrict__ wp) {
  int gi = blockIdx.x * 256 + threadIdx.x;
  int which = gi >> 14;
  int i = gi & 16383;
  const float* W = (which == 0) ? W1 : ((which == 1) ? W2 : W3);
  int j = i & 7;
  int l = (i >> 3) & 63;
  int kc = (i >> 9) & 3;
  int c = i >> 11;
  int k = kc * 32 + ((l >> 4) << 3) + j;
  int col = c * 16 + (l & 15);
  wp[gi] = __float2half_rn(W[k * FD + col]);
}

// MFMA GEMM: C[n x 128] = A[n x 128] @ W, fp16 storage, fp32 accum.
// Block: 64 rows, 256 threads = 4 waves; wave w owns rows [w*16, w*16+16).
// A in LDS (16KB, XOR-swizzled byte ^= (row&7)<<4); Wp in LDS (32KB).
// a_fp32: stage converts fp32->fp16 (layer 1 reads x directly).
// Epilogue: C tile staged in al4 (reused) then coalesced uint4 stores.
__global__ __launch_bounds__(256) void k_gemm_mfma(const void* __restrict__ Ain,
                                                   int a_fp32,
                                                   const __half* __restrict__ Wp,
                                                   __half* __restrict__ C, int n) {
  __shared__ uint4 al4[1024];  // 16 KB: A tile (swizzled), later C tile
  __shared__ uint4 wl4[2048];  // 32 KB: packed B-frags
  int tid = threadIdx.x;
  const uint4* wsrc = reinterpret_cast<const uint4*>(Wp);
  for (int i = tid; i < 2048; i += 256) wl4[i] = wsrc[i];

  int rb = blockIdx.x * 64;
  if (a_fp32) {
    const float* A = (const float*)Ain;
    for (int i = tid; i < 2048; i += 256) {  // 64 rows x 32 x (4 floats -> 8B)
      int row = i >> 5, seg = i & 31;
      int g = rb + row;
      if (g > n - 1) g = n - 1;
      float4 v = *reinterpret_cast<const float4*>(A + (size_t)g * FD + seg * 4);
      __half h[4];
      h[0] = __float2half_rn(v.x); h[1] = __float2half_rn(v.y);
      h[2] = __float2half_rn(v.z); h[3] = __float2half_rn(v.w);
      *reinterpret_cast<uint2*>(reinterpret_cast<char*>(al4) + row * 256 +
                                ((seg * 8) ^ ((row & 7) << 4))) =
          *reinterpret_cast<uint2*>(h);
    }
  } else {
    const __half* A = (const __half*)Ain;
    for (int i = tid; i < 1024; i += 256) {  // 64 rows x 16 x 16B
      int row = i >> 4, b = (i & 15) << 4;
      int g = rb + row;
      if (g > n - 1) g = n - 1;
      uint4 v = *reinterpret_cast<const uint4*>(
          reinterpret_cast<const char*>(A) + (size_t)g * 256 + b);
      *reinterpret_cast<uint4*>(reinterpret_cast<char*>(al4) + row * 256 +
                                (b ^ ((row & 7) << 4))) = v;
    }
  }
  __syncthreads();

  int l = tid & 63, wid = tid >> 6;
  int arow = wid * 16 + (l & 15);  // A-frag row (row = lane&15)
  f16x8 af[4];
#pragma unroll
  for (int kc = 0; kc < 4; ++kc) {
    int b = kc * 64 + ((l >> 4) << 4);  // k = kc*32 + 8*(l>>4), in bytes
    af[kc] = *reinterpret_cast<const f16x8*>(
        reinterpret_cast<const char*>(al4) + arow * 256 + (b ^ ((arow & 7) << 4)));
  }

  const __half* wl = reinterpret_cast<const __half*>(wl4);
  f32x4 acc[8];
#pragma unroll
  for (int c = 0; c < 8; ++c) acc[c] = (f32x4){0.f, 0.f, 0.f, 0.f};
#pragma unroll
  for (int c = 0; c < 8; ++c) {
#pragma unroll
    for (int kc = 0; kc < 4; ++kc) {
      f16x8 bf = *reinterpret_cast<const f16x8*>(&wl[((c * 4 + kc) * 64 + l) * 8]);
      acc[c] = __builtin_amdgcn_mfma_f32_16x16x32_f16(af[kc], bf, acc[c], 0, 0, 0);
    }
  }

  // C tile through LDS (al4 reused; all af reads completed before this barrier)
  __syncthreads();
  {
    char* cl = reinterpret_cast<char*>(al4);
    int crow0 = wid * 16 + ((l >> 4) << 2);
#pragma unroll
    for (int c = 0; c < 8; ++c) {
      int colb = (c * 16 + (l & 15)) * 2;
#pragma unroll
      for (int r = 0; r < 4; ++r) {
        int row = crow0 + r;
        *reinterpret_cast<__half*>(cl + row * 256 + (colb ^ ((row & 7) << 4))) =
            __float2half_rn(acc[c][r]);
      }
    }
  }
  __syncthreads();
  for (int i = tid; i < 1024; i += 256) {
    int row = i >> 4, seg = i & 15;
    int g = rb + row;
    if (g < n)
      *reinterpret_cast<uint4*>(reinterpret_cast<char*>(C) + (size_t)g * 256 +
                                seg * 16) =
          *reinterpret_cast<const uint4*>(reinterpret_cast<const char*>(al4) +
                                          row * 256 +
                                          ((seg * 16) ^ ((row & 7) << 4)));
  }
}

// Wave-level aggregation core: lane = (h = lane>>5 edge-parity, q = lane&31
// feature group of 4). Two edges per wave VMEM instruction.
__device__ __forceinline__ void agg_wave(const __half* __restrict__ t,
                                         const int* __restrict__ ptr,
                                         const int2* __restrict__ sn,
                                         int node, int lane, float o[4]) {
  int h = lane >> 5;
  int q = lane & 31;
  float a0 = 0.f, a1 = 0.f, a2 = 0.f, a3 = 0.f;
  int e0 = ptr[node], e1 = ptr[node + 1];
  for (int base = e0; base < e1; base += 16) {
    int s[8];
    float w[8];
#pragma unroll
    for (int j = 0; j < 8; ++j) {
      int idx = base + 2 * j + h;
      if (idx < e1) {
        int2 p = sn[idx];
        s[j] = p.x;
        w[j] = __int_as_float(p.y);
      } else {
        s[j] = node;
        w[j] = 0.f;
      }
    }
    ushort4 v[8];
#pragma unroll
    for (int j = 0; j < 8; ++j)
      v[j] = *reinterpret_cast<const ushort4*>(&t[(size_t)s[j] * FD + q * 4]);
#pragma unroll
    for (int j = 0; j < 8; ++j) {
      a0 = fmaf(__half2float(__ushort_as_half(v[j].x)), w[j], a0);
      a1 = fmaf(__half2float(__ushort_as_half(v[j].y)), w[j], a1);
      a2 = fmaf(__half2float(__ushort_as_half(v[j].z)), w[j], a2);
      a3 = fmaf(__half2float(__ushort_as_half(v[j].w)), w[j], a3);
    }
  }
  o[0] = a0 + __shfl(a0, lane ^ 32, 64);
  o[1] = a1 + __shfl(a1, lane ^ 32, 64);
  o[2] = a2 + __shfl(a2, lane ^ 32, 64);
  o[3] = a3 + __shfl(a3, lane ^ 32, 64);
}

// DIAGNOSTIC (correctness-neutral): same structure as agg_wave but gather
// index is node laundered through asm -> identical instruction stream, zero
// randomness, L1-hot row. Compares against k_agg's ~49us in top-5.
template <int SELF>
__global__ __launch_bounds__(256) void k_probe(const __half* __restrict__ t,
                                               const int* __restrict__ ptr,
                                               const int2* __restrict__ sn,
                                               float* __restrict__ pr) {
  int lane = threadIdx.x & 63;
  int node = blockIdx.x * 4 + (threadIdx.x >> 6);
  int h = lane >> 5, q = lane & 31;
  float a0 = 0.f, a1 = 0.f, a2 = 0.f, a3 = 0.f;
  int e0 = ptr[node], e1 = ptr[node + 1];
  for (int base = e0; base < e1; base += 16) {
    int s[8];
    float w[8];
#pragma unroll
    for (int j = 0; j < 8; ++j) {
      int idx = base + 2 * j + h;
      if (idx < e1) {
        int2 p = sn[idx];
        s[j] = p.x;
        w[j] = __int_as_float(p.y);
      } else {
        s[j] = node;
        w[j] = 0.f;
      }
      if (SELF) {
        int nd = node;
        asm volatile("" : "+v"(nd));  // opaque: keeps 8 distinct loads
        s[j] = nd;
      }
    }
    ushort4 v[8];
#pragma unroll
    for (int j = 0; j < 8; ++j)
      v[j] = *reinterpret_cast<const ushort4*>(&t[(size_t)s[j] * FD + q * 4]);
#pragma unroll
    for (int j = 0; j < 8; ++j) {
      a0 = fmaf(__half2float(__ushort_as_half(v[j].x)), w[j], a0);
      a1 = fmaf(__half2float(__ushort_as_half(v[j].y)), w[j], a1);
      a2 = fmaf(__half2float(__ushort_as_half(v[j].z)), w[j], a2);
      a3 = fmaf(__half2float(__ushort_as_half(v[j].w)), w[j], a3);
    }
  }
  a0 += __shfl(a0, lane ^ 32, 64);
  a1 += __shfl(a1, lane ^ 32, 64);
  a2 += __shfl(a2, lane ^ 32, 64);
  a3 += __shfl(a3, lane ^ 32, 64);
  if (lane < 32)
    *reinterpret_cast<float4*>(&pr[((size_t)node * 32 + q) * 4]) =
        make_float4(a0, a1, a2, a3);
}

// 4 nodes per 256-thread block (1 wave per node): agg + bias (+relu), fp16 out.
__global__ __launch_bounds__(256) void k_agg(const __half* __restrict__ t,
                                             const int* __restrict__ ptr,
                                             const int2* __restrict__ sn,
                                             const float* __restrict__ dis,
                                             const float* __restrict__ bias,
                                             __half* __restrict__ out, int relu) {
  int lane = threadIdx.x & 63;
  int node = blockIdx.x * 4 + (threadIdx.x >> 6);
  float d = dis[node];
  float dd = d * d;
  float o[4];
  agg_wave(t, ptr, sn, node, lane, o);
  if (lane < 32) {
    int q = lane;
    ushort4 sv = *reinterpret_cast<const ushort4*>(&t[(size_t)node * FD + q * 4]);
    float4 b = *reinterpret_cast<const float4*>(&bias[q * 4]);
    o[0] = fmaf(__half2float(__ushort_as_half(sv.x)), dd, o[0]) + b.x;
    o[1] = fmaf(__half2float(__ushort_as_half(sv.y)), dd, o[1]) + b.y;
    o[2] = fmaf(__half2float(__ushort_as_half(sv.z)), dd, o[2]) + b.z;
    o[3] = fmaf(__half2float(__ushort_as_half(sv.w)), dd, o[3]) + b.w;
    if (relu) {
      o[0] = fmaxf(o[0], 0.f);
      o[1] = fmaxf(o[1], 0.f);
      o[2] = fmaxf(o[2], 0.f);
      o[3] = fmaxf(o[3], 0.f);
    }
    __half hh[4];
    hh[0] = __float2half_rn(o[0]);
    hh[1] = __float2half_rn(o[1]);
    hh[2] = __float2half_rn(o[2]);
    hh[3] = __float2half_rn(o[3]);
    *reinterpret_cast<uint2*>(&out[(size_t)node * FD + q * 4]) =
        *reinterpret_cast<uint2*>(hh);
  }
}

// Last layer: agg + b3 into LDS, then fused h @ Wlin + blin -> out[node][16].
__global__ __launch_bounds__(256) void k_agg_lin(const __half* __restrict__ t,
                                                 const int* __restrict__ ptr,
                                                 const int2* __restrict__ sn,
                                                 const float* __restrict__ dis,
                                                 const float* __restrict__ b3,
                                                 const float* __restrict__ Wl,
                                                 const float* __restrict__ bl,
                                                 float* __restrict__ out) {
  __shared__ float hl[4][FD];
  int wid = threadIdx.x >> 6;
  int lane = threadIdx.x & 63;
  int node = blockIdx.x * 4 + wid;
  float d = dis[node];
  float dd = d * d;
  float o[4];
  agg_wave(t, ptr, sn, node, lane, o);
  if (lane < 32) {
    int q = lane;
    ushort4 sv = *reinterpret_cast<const ushort4*>(&t[(size_t)node * FD + q * 4]);
    float4 b = *reinterpret_cast<const float4*>(&b3[q * 4]);
    hl[wid][q * 4 + 0] = fmaf(__half2float(__ushort_as_half(sv.x)), dd, o[0]) + b.x;
    hl[wid][q * 4 + 1] = fmaf(__half2float(__ushort_as_half(sv.y)), dd, o[1]) + b.y;
    hl[wid][q * 4 + 2] = fmaf(__half2float(__ushort_as_half(sv.z)), dd, o[2]) + b.z;
    hl[wid][q * 4 + 3] = fmaf(__half2float(__ushort_as_half(sv.w)), dd, o[3]) + b.w;
  }
  __syncthreads();
  int c = lane & 15, kc = lane >> 4;
  float s = 0.f;
#pragma unroll
  for (int k0 = 0; k0 < 32; ++k0) {
    int k = kc * 32 + k0;
    s = fmaf(hl[wid][k], Wl[k * NCLS + c], s);
  }
  s += __shfl(s, lane ^ 16, 64);
  s += __shfl(s, lane ^ 32, 64);
  if (lane < NCLS)
    out[(size_t)node * NCLS + lane] = s + bl[lane];
}

extern "C" void kernel_launch(void* const* d_in, const int* in_sizes, int n_in,
                              void* d_out, int out_size, void* d_ws, size_t ws_size,
                              hipStream_t stream) {
  const float* x  = (const float*)d_in[0];
  const int*   ei = (const int*)d_in[1];
  const float* W1 = (const float*)d_in[2];
  const float* b1 = (const float*)d_in[3];
  const float* W2 = (const float*)d_in[4];
  const float* b2 = (const float*)d_in[5];
  const float* W3 = (const float*)d_in[6];
  const float* b3 = (const float*)d_in[7];
  const float* Wl = (const float*)d_in[8];
  const float* bl = (const float*)d_in[9];
  float* out = (float*)d_out;

  const int n = in_sizes[0] / FD;      // 50000
  const int e = in_sizes[1] / 2;       // 600000
  const int* src = ei;                 // edge_index[0]
  const int* dst = ei + e;             // edge_index[1]

  // workspace carve: thA | thB (half, n*FD each) | pr (float, n*32*4) | wp1..3
  __half* thA = (__half*)d_ws;                        // n*FD halves
  __half* thB = thA + (size_t)n * FD;                 // n*FD halves
  float*  pr  = (float*)(thB + (size_t)n * FD);       // n*FD floats (probe dump)
  __half* wp1 = (__half*)(pr + (size_t)n * FD);       // 16384
  __half* wp2 = wp1 + 16384;                          // 16384
  __half* wp3 = wp2 + 16384;                          // 16384
  int*   degi = (int*)(wp3 + 16384);                  // n
  float* dis  = (float*)(degi + n);                   // n
  int*   ptr  = (int*)(dis + n);                      // n+1
  int*   cur  = ptr + n + 1;                          // n
  int*   bsum = cur + n;                              // <=64
  int2*  sn   = (int2*)(((uintptr_t)(bsum + 64) + 15) & ~(uintptr_t)15);  // e

  const int gn = (n + 255) / 256;
  const int ge = (e + 255) / 256;
  const int nb = (n + 1023) / 1024;

  k_init_deg<<<gn, 256, 0, stream>>>(degi, n);
  k_count<<<ge, 256, 0, stream>>>(dst, degi, e);
  k_scanA<<<nb, 1024, 0, stream>>>(degi, ptr, bsum, dis, n);
  k_scanB<<<1, 64, 0, stream>>>(bsum, nb);
  k_scanC<<<gn, 256, 0, stream>>>(ptr, cur, bsum, n, e);
  k_fill<<<ge, 256, 0, stream>>>(src, dst, cur, dis, sn, e);
  k_convW3<<<192, 256, 0, stream>>>(W1, W2, W3, wp1);

  const int gG = (n + 63) / 64;  // 782 row-tiles
  const int ga = n / 4;          // 12500 blocks, 4 nodes (waves) each

  k_gemm_mfma<<<gG, 256, 0, stream>>>(x, 1, wp1, thA, n);
  k_agg<<<ga, 256, 0, stream>>>(thA, ptr, sn, dis, b1, thB, 1);
  k_gemm_mfma<<<gG, 256, 0, stream>>>(thB, 0, wp2, thA, n);
  k_agg<<<ga, 256, 0, stream>>>(thA, ptr, sn, dis, b2, thB, 1);
  k_gemm_mfma<<<gG, 256, 0, stream>>>(thB, 0, wp3, thA, n);
  k_agg_lin<<<ga, 256, 0, stream>>>(thA, ptr, sn, dis, b3, Wl, bl, out);

  // diagnostic (output unused, full grid so it is visible in top-5 iff slow)
  k_probe<1><<<ga, 256, 0, stream>>>(thA, ptr, sn, pr);
}

// Round 11
// 333.737 us; speedup vs baseline: 1.0076x; 1.0076x over previous
//
#include <hip/hip_runtime.h>
#include <hip/hip_fp16.h>

// 3-layer GCN (PyG GCNConv semantics): deg/norm build -> CSR by dst ->
// layer1: MFMA GEMM (x fp32 -> fp16) then agg+relu; layer2: same on h1;
// layer3: associativity-fused -- (A h2)(W3 Wl) + (b3 Wl + bl) -- so the
// third GEMM disappears into a 128x16 per-node matmul inside agg_lin.
//
// R11: probe removed (R10 verdict: agg is randomness-bound, near the
// per-XCD distinct-row fetch floor; structure cost is minor). W3'=W3*Wl
// precomputed by k_fuse3. Aggs are grid-stride persistent (2048 blocks =
// 8/CU) to raise occupancy 72% -> ~90%.

#define FD 128
#define NCLS 16

typedef _Float16 f16x8 __attribute__((ext_vector_type(8)));
typedef float f32x4 __attribute__((ext_vector_type(4)));

__global__ __launch_bounds__(256) void k_init_deg(int* __restrict__ degi, int n) {
  int i = blockIdx.x * 256 + threadIdx.x;
  if (i < n) degi[i] = 1;  // self-loop
}

__global__ __launch_bounds__(256) void k_count(const int* __restrict__ dst,
                                               int* __restrict__ degi, int e) {
  int i = blockIdx.x * 256 + threadIdx.x;
  if (i < e) atomicAdd(&degi[dst[i]], 1);
}

// Phase A: per-1024-chunk exclusive scan of (deg-1); also emits dis=rsqrt(deg)
__global__ __launch_bounds__(1024) void k_scanA(const int* __restrict__ degi,
                                                int* __restrict__ ptr,
                                                int* __restrict__ bsum,
                                                float* __restrict__ dis, int n) {
  __shared__ int buf[1024];
  int tid = threadIdx.x;
  int i = blockIdx.x * 1024 + tid;
  int dg = (i < n) ? degi[i] : 1;
  if (i < n) dis[i] = rsqrtf((float)dg);
  int v = (i < n) ? (dg - 1) : 0;
  buf[tid] = v;
  __syncthreads();
  for (int off = 1; off < 1024; off <<= 1) {
    int t = (tid >= off) ? buf[tid - off] : 0;
    __syncthreads();
    buf[tid] += t;
    __syncthreads();
  }
  if (i < n) ptr[i] = buf[tid] - v;  // local exclusive
  if (tid == 1023) bsum[blockIdx.x] = buf[1023];
}

// Phase B: tiny serial scan of ~49 block sums
__global__ void k_scanB(int* __restrict__ bsum, int nb) {
  if (threadIdx.x == 0 && blockIdx.x == 0) {
    int run = 0;
    for (int b = 0; b < nb; ++b) { int t = bsum[b]; bsum[b] = run; run += t; }
  }
}

// Phase C: add chunk offsets, init fill cursors, write ptr[n]
__global__ __launch_bounds__(256) void k_scanC(int* __restrict__ ptr,
                                               int* __restrict__ cur,
                                               const int* __restrict__ bsum,
                                               int n, int e) {
  int i = blockIdx.x * 256 + threadIdx.x;
  if (i < n) {
    int p = ptr[i] + bsum[i >> 10];
    ptr[i] = p;
    cur[i] = p;
  }
  if (i == 0) ptr[n] = e;
}

__global__ __launch_bounds__(256) void k_fill(const int* __restrict__ src,
                                              const int* __restrict__ dst,
                                              int* __restrict__ cur,
                                              const float* __restrict__ dis,
                                              int2* __restrict__ sn, int e) {
  int i = blockIdx.x * 256 + threadIdx.x;
  if (i < e) {
    int s = src[i], d = dst[i];
    int p = atomicAdd(&cur[d], 1);
    sn[p] = make_int2(s, __float_as_int(dis[s] * dis[d]));
  }
}

// Pack W1,W2 (128x128 fp32 row-major) into per-lane B-fragment order:
// wp[((c*4+kc)*64 + l)*8 + j] = W[kc*32 + (l>>4)*8 + j][c*16 + (l&15)].
// grid = 128 blocks x 256 = 2 x 16384.
__global__ __launch_bounds__(256) void k_convW2(const float* __restrict__ W1,
                                                const float* __restrict__ W2,
                                                __half* __restrict__ wp) {
  int gi = blockIdx.x * 256 + threadIdx.x;
  int which = gi >> 14;
  int i = gi & 16383;
  const float* W = (which == 0) ? W1 : W2;
  int j = i & 7;
  int l = (i >> 3) & 63;
  int kc = (i >> 9) & 3;
  int c = i >> 11;
  int k = kc * 32 + ((l >> 4) << 3) + j;
  int col = c * 16 + (l & 15);
  wp[gi] = __float2half_rn(W[k * FD + col]);
}

// W3' = W3 @ Wl (128x16), b3' = b3 @ Wl + bl (16). One block, 256 threads,
// 8 cells/thread (2048 = 128x16), thread tid<16 also does b3'.
__global__ __launch_bounds__(256) void k_fuse3(const float* __restrict__ W3,
                                               const float* __restrict__ Wl,
                                               const float* __restrict__ b3,
                                               const float* __restrict__ bl,
                                               float* __restrict__ W3p,
                                               float* __restrict__ b3p) {
  int tid = threadIdx.x;
  for (int i = tid; i < FD * NCLS; i += 256) {
    int k = i >> 4, c = i & 15;
    float s = 0.f;
#pragma unroll 8
    for (int m = 0; m < FD; ++m)
      s = fmaf(W3[k * FD + m], Wl[m * NCLS + c], s);
    W3p[i] = s;
  }
  if (tid < NCLS) {
    float s = bl[tid];
    for (int m = 0; m < FD; ++m)
      s = fmaf(b3[m], Wl[m * NCLS + tid], s);
    b3p[tid] = s;
  }
}

// MFMA GEMM: C[n x 128] = A[n x 128] @ W, fp16 storage, fp32 accum.
// Block: 64 rows, 256 threads = 4 waves; wave w owns rows [w*16, w*16+16).
// A in LDS (16KB, XOR-swizzled byte ^= (row&7)<<4); Wp in LDS (32KB).
// a_fp32: stage converts fp32->fp16 (layer 1 reads x directly).
// Epilogue: C tile staged in al4 (reused) then coalesced uint4 stores.
__global__ __launch_bounds__(256) void k_gemm_mfma(const void* __restrict__ Ain,
                                                   int a_fp32,
                                                   const __half* __restrict__ Wp,
                                                   __half* __restrict__ C, int n) {
  __shared__ uint4 al4[1024];  // 16 KB: A tile (swizzled), later C tile
  __shared__ uint4 wl4[2048];  // 32 KB: packed B-frags
  int tid = threadIdx.x;
  const uint4* wsrc = reinterpret_cast<const uint4*>(Wp);
  for (int i = tid; i < 2048; i += 256) wl4[i] = wsrc[i];

  int rb = blockIdx.x * 64;
  if (a_fp32) {
    const float* A = (const float*)Ain;
    for (int i = tid; i < 2048; i += 256) {  // 64 rows x 32 x (4 floats -> 8B)
      int row = i >> 5, seg = i & 31;
      int g = rb + row;
      if (g > n - 1) g = n - 1;
      float4 v = *reinterpret_cast<const float4*>(A + (size_t)g * FD + seg * 4);
      __half h[4];
      h[0] = __float2half_rn(v.x); h[1] = __float2half_rn(v.y);
      h[2] = __float2half_rn(v.z); h[3] = __float2half_rn(v.w);
      *reinterpret_cast<uint2*>(reinterpret_cast<char*>(al4) + row * 256 +
                                ((seg * 8) ^ ((row & 7) << 4))) =
          *reinterpret_cast<uint2*>(h);
    }
  } else {
    const __half* A = (const __half*)Ain;
    for (int i = tid; i < 1024; i += 256) {  // 64 rows x 16 x 16B
      int row = i >> 4, b = (i & 15) << 4;
      int g = rb + row;
      if (g > n - 1) g = n - 1;
      uint4 v = *reinterpret_cast<const uint4*>(
          reinterpret_cast<const char*>(A) + (size_t)g * 256 + b);
      *reinterpret_cast<uint4*>(reinterpret_cast<char*>(al4) + row * 256 +
                                (b ^ ((row & 7) << 4))) = v;
    }
  }
  __syncthreads();

  int l = tid & 63, wid = tid >> 6;
  int arow = wid * 16 + (l & 15);  // A-frag row (row = lane&15)
  f16x8 af[4];
#pragma unroll
  for (int kc = 0; kc < 4; ++kc) {
    int b = kc * 64 + ((l >> 4) << 4);  // k = kc*32 + 8*(l>>4), in bytes
    af[kc] = *reinterpret_cast<const f16x8*>(
        reinterpret_cast<const char*>(al4) + arow * 256 + (b ^ ((arow & 7) << 4)));
  }

  const __half* wl = reinterpret_cast<const __half*>(wl4);
  f32x4 acc[8];
#pragma unroll
  for (int c = 0; c < 8; ++c) acc[c] = (f32x4){0.f, 0.f, 0.f, 0.f};
#pragma unroll
  for (int c = 0; c < 8; ++c) {
#pragma unroll
    for (int kc = 0; kc < 4; ++kc) {
      f16x8 bf = *reinterpret_cast<const f16x8*>(&wl[((c * 4 + kc) * 64 + l) * 8]);
      acc[c] = __builtin_amdgcn_mfma_f32_16x16x32_f16(af[kc], bf, acc[c], 0, 0, 0);
    }
  }

  // C tile through LDS (al4 reused; all af reads completed before this barrier)
  __syncthreads();
  {
    char* cl = reinterpret_cast<char*>(al4);
    int crow0 = wid * 16 + ((l >> 4) << 2);
#pragma unroll
    for (int c = 0; c < 8; ++c) {
      int colb = (c * 16 + (l & 15)) * 2;
#pragma unroll
      for (int r = 0; r < 4; ++r) {
        int row = crow0 + r;
        *reinterpret_cast<__half*>(cl + row * 256 + (colb ^ ((row & 7) << 4))) =
            __float2half_rn(acc[c][r]);
      }
    }
  }
  __syncthreads();
  for (int i = tid; i < 1024; i += 256) {
    int row = i >> 4, seg = i & 15;
    int g = rb + row;
    if (g < n)
      *reinterpret_cast<uint4*>(reinterpret_cast<char*>(C) + (size_t)g * 256 +
                                seg * 16) =
          *reinterpret_cast<const uint4*>(reinterpret_cast<const char*>(al4) +
                                          row * 256 +
                                          ((seg * 16) ^ ((row & 7) << 4)));
  }
}

// Wave-level aggregation core: lane = (h = lane>>5 edge-parity, q = lane&31
// feature group of 4). Two edges per wave VMEM instruction.
__device__ __forceinline__ void agg_wave(const __half* __restrict__ t,
                                         const int* __restrict__ ptr,
                                         const int2* __restrict__ sn,
                                         int node, int lane, float o[4]) {
  int h = lane >> 5;
  int q = lane & 31;
  float a0 = 0.f, a1 = 0.f, a2 = 0.f, a3 = 0.f;
  int e0 = ptr[node], e1 = ptr[node + 1];
  for (int base = e0; base < e1; base += 16) {
    int s[8];
    float w[8];
#pragma unroll
    for (int j = 0; j < 8; ++j) {
      int idx = base + 2 * j + h;
      if (idx < e1) {
        int2 p = sn[idx];
        s[j] = p.x;
        w[j] = __int_as_float(p.y);
      } else {
        s[j] = node;
        w[j] = 0.f;
      }
    }
    ushort4 v[8];
#pragma unroll
    for (int j = 0; j < 8; ++j)
      v[j] = *reinterpret_cast<const ushort4*>(&t[(size_t)s[j] * FD + q * 4]);
#pragma unroll
    for (int j = 0; j < 8; ++j) {
      a0 = fmaf(__half2float(__ushort_as_half(v[j].x)), w[j], a0);
      a1 = fmaf(__half2float(__ushort_as_half(v[j].y)), w[j], a1);
      a2 = fmaf(__half2float(__ushort_as_half(v[j].z)), w[j], a2);
      a3 = fmaf(__half2float(__ushort_as_half(v[j].w)), w[j], a3);
    }
  }
  o[0] = a0 + __shfl(a0, lane ^ 32, 64);
  o[1] = a1 + __shfl(a1, lane ^ 32, 64);
  o[2] = a2 + __shfl(a2, lane ^ 32, 64);
  o[3] = a3 + __shfl(a3, lane ^ 32, 64);
}

// Grid-stride persistent agg: 1 wave per node, 4 nodes per block per sweep.
// n % 4 == 0 -> all waves of an entered sweep are valid.
__global__ __launch_bounds__(256) void k_agg(const __half* __restrict__ t,
                                             const int* __restrict__ ptr,
                                             const int2* __restrict__ sn,
                                             const float* __restrict__ dis,
                                             const float* __restrict__ bias,
                                             __half* __restrict__ out, int relu,
                                             int n) {
  int lane = threadIdx.x & 63;
  int wid = threadIdx.x >> 6;
  int stride = gridDim.x * 4;
  for (int node0 = blockIdx.x * 4; node0 < n; node0 += stride) {
    int node = node0 + wid;
    float d = dis[node];
    float dd = d * d;
    float o[4];
    agg_wave(t, ptr, sn, node, lane, o);
    if (lane < 32) {
      int q = lane;
      ushort4 sv =
          *reinterpret_cast<const ushort4*>(&t[(size_t)node * FD + q * 4]);
      float4 b = *reinterpret_cast<const float4*>(&bias[q * 4]);
      o[0] = fmaf(__half2float(__ushort_as_half(sv.x)), dd, o[0]) + b.x;
      o[1] = fmaf(__half2float(__ushort_as_half(sv.y)), dd, o[1]) + b.y;
      o[2] = fmaf(__half2float(__ushort_as_half(sv.z)), dd, o[2]) + b.z;
      o[3] = fmaf(__half2float(__ushort_as_half(sv.w)), dd, o[3]) + b.w;
      if (relu) {
        o[0] = fmaxf(o[0], 0.f);
        o[1] = fmaxf(o[1], 0.f);
        o[2] = fmaxf(o[2], 0.f);
        o[3] = fmaxf(o[3], 0.f);
      }
      __half hh[4];
      hh[0] = __float2half_rn(o[0]);
      hh[1] = __float2half_rn(o[1]);
      hh[2] = __float2half_rn(o[2]);
      hh[3] = __float2half_rn(o[3]);
      *reinterpret_cast<uint2*>(&out[(size_t)node * FD + q * 4]) =
          *reinterpret_cast<uint2*>(hh);
    }
  }
}

// Layer 3 fused: agg(h2) into LDS, then per-node 128x16 matmul with
// W3' (=W3@Wl) + b3' (=b3@Wl+bl) -> out[node][16]. Grid-stride.
__global__ __launch_bounds__(256) void k_agg_lin(const __half* __restrict__ t,
                                                 const int* __restrict__ ptr,
                                                 const int2* __restrict__ sn,
                                                 const float* __restrict__ dis,
                                                 const float* __restrict__ W3p,
                                                 const float* __restrict__ b3p,
                                                 float* __restrict__ out, int n) {
  __shared__ float hl[4][FD];
  int wid = threadIdx.x >> 6;
  int lane = threadIdx.x & 63;
  int stride = gridDim.x * 4;
  for (int node0 = blockIdx.x * 4; node0 < n; node0 += stride) {
    int node = node0 + wid;
    float d = dis[node];
    float dd = d * d;
    float o[4];
    agg_wave(t, ptr, sn, node, lane, o);
    if (lane < 32) {
      int q = lane;
      ushort4 sv =
          *reinterpret_cast<const ushort4*>(&t[(size_t)node * FD + q * 4]);
      hl[wid][q * 4 + 0] = fmaf(__half2float(__ushort_as_half(sv.x)), dd, o[0]);
      hl[wid][q * 4 + 1] = fmaf(__half2float(__ushort_as_half(sv.y)), dd, o[1]);
      hl[wid][q * 4 + 2] = fmaf(__half2float(__ushort_as_half(sv.z)), dd, o[2]);
      hl[wid][q * 4 + 3] = fmaf(__half2float(__ushort_as_half(sv.w)), dd, o[3]);
    }
    __syncthreads();
    int c = lane & 15, kc = lane >> 4;
    float s = 0.f;
#pragma unroll
    for (int k0 = 0; k0 < 32; ++k0) {
      int k = kc * 32 + k0;
      s = fmaf(hl[wid][k], W3p[k * NCLS + c], s);
    }
    s += __shfl(s, lane ^ 16, 64);
    s += __shfl(s, lane ^ 32, 64);
    if (lane < NCLS)
      out[(size_t)node * NCLS + lane] = s + b3p[lane];
    __syncthreads();  // hl reused next sweep
  }
}

extern "C" void kernel_launch(void* const* d_in, const int* in_sizes, int n_in,
                              void* d_out, int out_size, void* d_ws, size_t ws_size,
                              hipStream_t stream) {
  const float* x  = (const float*)d_in[0];
  const int*   ei = (const int*)d_in[1];
  const float* W1 = (const float*)d_in[2];
  const float* b1 = (const float*)d_in[3];
  const float* W2 = (const float*)d_in[4];
  const float* b2 = (const float*)d_in[5];
  const float* W3 = (const float*)d_in[6];
  const float* b3 = (const float*)d_in[7];
  const float* Wl = (const float*)d_in[8];
  const float* bl = (const float*)d_in[9];
  float* out = (float*)d_out;

  const int n = in_sizes[0] / FD;      // 50000
  const int e = in_sizes[1] / 2;       // 600000
  const int* src = ei;                 // edge_index[0]
  const int* dst = ei + e;             // edge_index[1]

  // workspace carve
  __half* thA = (__half*)d_ws;                        // n*FD halves
  __half* thB = thA + (size_t)n * FD;                 // n*FD halves
  __half* wp1 = thB + (size_t)n * FD;                 // 16384 (W1 packed)
  __half* wp2 = wp1 + 16384;                          // 16384 (W2 packed)
  float*  W3p = (float*)(wp2 + 16384);                // 2048
  float*  b3p = W3p + 2048;                           // 16
  int*   degi = (int*)(b3p + 16);                     // n
  float* dis  = (float*)(degi + n);                   // n
  int*   ptr  = (int*)(dis + n);                      // n+1
  int*   cur  = ptr + n + 1;                          // n
  int*   bsum = cur + n;                              // <=64
  int2*  sn   = (int2*)(((uintptr_t)(bsum + 64) + 15) & ~(uintptr_t)15);  // e

  const int gn = (n + 255) / 256;
  const int ge = (e + 255) / 256;
  const int nb = (n + 1023) / 1024;

  k_init_deg<<<gn, 256, 0, stream>>>(degi, n);
  k_count<<<ge, 256, 0, stream>>>(dst, degi, e);
  k_scanA<<<nb, 1024, 0, stream>>>(degi, ptr, bsum, dis, n);
  k_scanB<<<1, 64, 0, stream>>>(bsum, nb);
  k_scanC<<<gn, 256, 0, stream>>>(ptr, cur, bsum, n, e);
  k_fill<<<ge, 256, 0, stream>>>(src, dst, cur, dis, sn, e);
  k_convW2<<<128, 256, 0, stream>>>(W1, W2, wp1);
  k_fuse3<<<1, 256, 0, stream>>>(W3, Wl, b3, bl, W3p, b3p);

  const int gG = (n + 63) / 64;  // 782 row-tiles
  const int ga = 2048;           // persistent: 8 blocks/CU x 256 CU

  k_gemm_mfma<<<gG, 256, 0, stream>>>(x, 1, wp1, thA, n);
  k_agg<<<ga, 256, 0, stream>>>(thA, ptr, sn, dis, b1, thB, 1, n);
  k_gemm_mfma<<<gG, 256, 0, stream>>>(thB, 0, wp2, thA, n);
  k_agg<<<ga, 256, 0, stream>>>(thA, ptr, sn, dis, b2, thB, 1, n);
  k_agg_lin<<<ga, 256, 0, stream>>>(thB, ptr, sn, dis, W3p, b3p, out, n);
}

// Round 13
// 325.786 us; speedup vs baseline: 1.0322x; 1.0244x over previous
//
#include <hip/hip_runtime.h>
#include <hip/hip_fp16.h>

// 3-layer GCN (PyG GCNConv semantics): deg/norm build -> CSR by dst ->
// layer1: MFMA GEMM (x fp32 -> fp16) then agg+relu; layer2: same on h1;
// layer3: associativity-fused -- (A h2)(W3 Wl) + (b3 Wl + bl) -- so the
// third GEMM is a 128x16 per-node matmul inside agg_lin.
//
// R12 (resubmit after broker timeout): revert R11's persistent grid-stride
// aggs (they DROPPED occupancy 72->37% and cost +21% time; one-shot
// 4-nodes/block is the better point); keep GEMM3 fusion; k_init_deg
// replaced by hipMemsetAsync (deg = count+1 in scanA).

#define FD 128
#define NCLS 16

typedef _Float16 f16x8 __attribute__((ext_vector_type(8)));
typedef float f32x4 __attribute__((ext_vector_type(4)));

__global__ __launch_bounds__(256) void k_count(const int* __restrict__ dst,
                                               int* __restrict__ degi, int e) {
  int i = blockIdx.x * 256 + threadIdx.x;
  if (i < e) atomicAdd(&degi[dst[i]], 1);
}

// Phase A: per-1024-chunk exclusive scan of in-edge counts; dis=rsqrt(cnt+1)
__global__ __launch_bounds__(1024) void k_scanA(const int* __restrict__ degi,
                                                int* __restrict__ ptr,
                                                int* __restrict__ bsum,
                                                float* __restrict__ dis, int n) {
  __shared__ int buf[1024];
  int tid = threadIdx.x;
  int i = blockIdx.x * 1024 + tid;
  int v = (i < n) ? degi[i] : 0;  // in-edge count (self-loop excluded)
  if (i < n) dis[i] = rsqrtf((float)(v + 1));
  buf[tid] = v;
  __syncthreads();
  for (int off = 1; off < 1024; off <<= 1) {
    int t = (tid >= off) ? buf[tid - off] : 0;
    __syncthreads();
    buf[tid] += t;
    __syncthreads();
  }
  if (i < n) ptr[i] = buf[tid] - v;  // local exclusive
  if (tid == 1023) bsum[blockIdx.x] = buf[1023];
}

// Phase B: tiny serial scan of ~49 block sums
__global__ void k_scanB(int* __restrict__ bsum, int nb) {
  if (threadIdx.x == 0 && blockIdx.x == 0) {
    int run = 0;
    for (int b = 0; b < nb; ++b) { int t = bsum[b]; bsum[b] = run; run += t; }
  }
}

// Phase C: add chunk offsets, init fill cursors, write ptr[n]
__global__ __launch_bounds__(256) void k_scanC(int* __restrict__ ptr,
                                               int* __restrict__ cur,
                                               const int* __restrict__ bsum,
                                               int n, int e) {
  int i = blockIdx.x * 256 + threadIdx.x;
  if (i < n) {
    int p = ptr[i] + bsum[i >> 10];
    ptr[i] = p;
    cur[i] = p;
  }
  if (i == 0) ptr[n] = e;
}

__global__ __launch_bounds__(256) void k_fill(const int* __restrict__ src,
                                              const int* __restrict__ dst,
                                              int* __restrict__ cur,
                                              const float* __restrict__ dis,
                                              int2* __restrict__ sn, int e) {
  int i = blockIdx.x * 256 + threadIdx.x;
  if (i < e) {
    int s = src[i], d = dst[i];
    int p = atomicAdd(&cur[d], 1);
    sn[p] = make_int2(s, __float_as_int(dis[s] * dis[d]));
  }
}

// Pack W1,W2 (128x128 fp32 row-major) into per-lane B-fragment order:
// wp[((c*4+kc)*64 + l)*8 + j] = W[kc*32 + (l>>4)*8 + j][c*16 + (l&15)].
// grid = 128 blocks x 256 = 2 x 16384.
__global__ __launch_bounds__(256) void k_convW2(const float* __restrict__ W1,
                                                const float* __restrict__ W2,
                                                __half* __restrict__ wp) {
  int gi = blockIdx.x * 256 + threadIdx.x;
  int which = gi >> 14;
  int i = gi & 16383;
  const float* W = (which == 0) ? W1 : W2;
  int j = i & 7;
  int l = (i >> 3) & 63;
  int kc = (i >> 9) & 3;
  int c = i >> 11;
  int k = kc * 32 + ((l >> 4) << 3) + j;
  int col = c * 16 + (l & 15);
  wp[gi] = __float2half_rn(W[k * FD + col]);
}

// W3' = W3 @ Wl (128x16), b3' = b3 @ Wl + bl (16). One block, 256 threads.
__global__ __launch_bounds__(256) void k_fuse3(const float* __restrict__ W3,
                                               const float* __restrict__ Wl,
                                               const float* __restrict__ b3,
                                               const float* __restrict__ bl,
                                               float* __restrict__ W3p,
                                               float* __restrict__ b3p) {
  int tid = threadIdx.x;
  for (int i = tid; i < FD * NCLS; i += 256) {
    int k = i >> 4, c = i & 15;
    float s = 0.f;
#pragma unroll 8
    for (int m = 0; m < FD; ++m)
      s = fmaf(W3[k * FD + m], Wl[m * NCLS + c], s);
    W3p[i] = s;
  }
  if (tid < NCLS) {
    float s = bl[tid];
    for (int m = 0; m < FD; ++m)
      s = fmaf(b3[m], Wl[m * NCLS + tid], s);
    b3p[tid] = s;
  }
}

// MFMA GEMM: C[n x 128] = A[n x 128] @ W, fp16 storage, fp32 accum.
// Block: 64 rows, 256 threads = 4 waves; wave w owns rows [w*16, w*16+16).
// A in LDS (16KB, XOR-swizzled byte ^= (row&7)<<4); Wp in LDS (32KB).
// a_fp32: stage converts fp32->fp16 (layer 1 reads x directly).
// Epilogue: C tile staged in al4 (reused) then coalesced uint4 stores.
__global__ __launch_bounds__(256) void k_gemm_mfma(const void* __restrict__ Ain,
                                                   int a_fp32,
                                                   const __half* __restrict__ Wp,
                                                   __half* __restrict__ C, int n) {
  __shared__ uint4 al4[1024];  // 16 KB: A tile (swizzled), later C tile
  __shared__ uint4 wl4[2048];  // 32 KB: packed B-frags
  int tid = threadIdx.x;
  const uint4* wsrc = reinterpret_cast<const uint4*>(Wp);
  for (int i = tid; i < 2048; i += 256) wl4[i] = wsrc[i];

  int rb = blockIdx.x * 64;
  if (a_fp32) {
    const float* A = (const float*)Ain;
    for (int i = tid; i < 2048; i += 256) {  // 64 rows x 32 x (4 floats -> 8B)
      int row = i >> 5, seg = i & 31;
      int g = rb + row;
      if (g > n - 1) g = n - 1;
      float4 v = *reinterpret_cast<const float4*>(A + (size_t)g * FD + seg * 4);
      __half h[4];
      h[0] = __float2half_rn(v.x); h[1] = __float2half_rn(v.y);
      h[2] = __float2half_rn(v.z); h[3] = __float2half_rn(v.w);
      *reinterpret_cast<uint2*>(reinterpret_cast<char*>(al4) + row * 256 +
                                ((seg * 8) ^ ((row & 7) << 4))) =
          *reinterpret_cast<uint2*>(h);
    }
  } else {
    const __half* A = (const __half*)Ain;
    for (int i = tid; i < 1024; i += 256) {  // 64 rows x 16 x 16B
      int row = i >> 4, b = (i & 15) << 4;
      int g = rb + row;
      if (g > n - 1) g = n - 1;
      uint4 v = *reinterpret_cast<const uint4*>(
          reinterpret_cast<const char*>(A) + (size_t)g * 256 + b);
      *reinterpret_cast<uint4*>(reinterpret_cast<char*>(al4) + row * 256 +
                                (b ^ ((row & 7) << 4))) = v;
    }
  }
  __syncthreads();

  int l = tid & 63, wid = tid >> 6;
  int arow = wid * 16 + (l & 15);  // A-frag row (row = lane&15)
  f16x8 af[4];
#pragma unroll
  for (int kc = 0; kc < 4; ++kc) {
    int b = kc * 64 + ((l >> 4) << 4);  // k = kc*32 + 8*(l>>4), in bytes
    af[kc] = *reinterpret_cast<const f16x8*>(
        reinterpret_cast<const char*>(al4) + arow * 256 + (b ^ ((arow & 7) << 4)));
  }

  const __half* wl = reinterpret_cast<const __half*>(wl4);
  f32x4 acc[8];
#pragma unroll
  for (int c = 0; c < 8; ++c) acc[c] = (f32x4){0.f, 0.f, 0.f, 0.f};
#pragma unroll
  for (int c = 0; c < 8; ++c) {
#pragma unroll
    for (int kc = 0; kc < 4; ++kc) {
      f16x8 bf = *reinterpret_cast<const f16x8*>(&wl[((c * 4 + kc) * 64 + l) * 8]);
      acc[c] = __builtin_amdgcn_mfma_f32_16x16x32_f16(af[kc], bf, acc[c], 0, 0, 0);
    }
  }

  // C tile through LDS (al4 reused; all af reads completed before this barrier)
  __syncthreads();
  {
    char* cl = reinterpret_cast<char*>(al4);
    int crow0 = wid * 16 + ((l >> 4) << 2);
#pragma unroll
    for (int c = 0; c < 8; ++c) {
      int colb = (c * 16 + (l & 15)) * 2;
#pragma unroll
      for (int r = 0; r < 4; ++r) {
        int row = crow0 + r;
        *reinterpret_cast<__half*>(cl + row * 256 + (colb ^ ((row & 7) << 4))) =
            __float2half_rn(acc[c][r]);
      }
    }
  }
  __syncthreads();
  for (int i = tid; i < 1024; i += 256) {
    int row = i >> 4, seg = i & 15;
    int g = rb + row;
    if (g < n)
      *reinterpret_cast<uint4*>(reinterpret_cast<char*>(C) + (size_t)g * 256 +
                                seg * 16) =
          *reinterpret_cast<const uint4*>(reinterpret_cast<const char*>(al4) +
                                          row * 256 +
                                          ((seg * 16) ^ ((row & 7) << 4)));
  }
}

// Wave-level aggregation core: lane = (h = lane>>5 edge-parity, q = lane&31
// feature group of 4). Two edges per wave VMEM instruction.
__device__ __forceinline__ void agg_wave(const __half* __restrict__ t,
                                         const int* __restrict__ ptr,
                                         const int2* __restrict__ sn,
                                         int node, int lane, float o[4]) {
  int h = lane >> 5;
  int q = lane & 31;
  float a0 = 0.f, a1 = 0.f, a2 = 0.f, a3 = 0.f;
  int e0 = ptr[node], e1 = ptr[node + 1];
  for (int base = e0; base < e1; base += 16) {
    int s[8];
    float w[8];
#pragma unroll
    for (int j = 0; j < 8; ++j) {
      int idx = base + 2 * j + h;
      if (idx < e1) {
        int2 p = sn[idx];
        s[j] = p.x;
        w[j] = __int_as_float(p.y);
      } else {
        s[j] = node;
        w[j] = 0.f;
      }
    }
    ushort4 v[8];
#pragma unroll
    for (int j = 0; j < 8; ++j)
      v[j] = *reinterpret_cast<const ushort4*>(&t[(size_t)s[j] * FD + q * 4]);
#pragma unroll
    for (int j = 0; j < 8; ++j) {
      a0 = fmaf(__half2float(__ushort_as_half(v[j].x)), w[j], a0);
      a1 = fmaf(__half2float(__ushort_as_half(v[j].y)), w[j], a1);
      a2 = fmaf(__half2float(__ushort_as_half(v[j].z)), w[j], a2);
      a3 = fmaf(__half2float(__ushort_as_half(v[j].w)), w[j], a3);
    }
  }
  o[0] = a0 + __shfl(a0, lane ^ 32, 64);
  o[1] = a1 + __shfl(a1, lane ^ 32, 64);
  o[2] = a2 + __shfl(a2, lane ^ 32, 64);
  o[3] = a3 + __shfl(a3, lane ^ 32, 64);
}

// 4 nodes per 256-thread block (1 wave per node): agg + bias (+relu), fp16 out.
__global__ __launch_bounds__(256) void k_agg(const __half* __restrict__ t,
                                             const int* __restrict__ ptr,
                                             const int2* __restrict__ sn,
                                             const float* __restrict__ dis,
                                             const float* __restrict__ bias,
                                             __half* __restrict__ out, int relu) {
  int lane = threadIdx.x & 63;
  int node = blockIdx.x * 4 + (threadIdx.x >> 6);
  float d = dis[node];
  float dd = d * d;
  float o[4];
  agg_wave(t, ptr, sn, node, lane, o);
  if (lane < 32) {
    int q = lane;
    ushort4 sv = *reinterpret_cast<const ushort4*>(&t[(size_t)node * FD + q * 4]);
    float4 b = *reinterpret_cast<const float4*>(&bias[q * 4]);
    o[0] = fmaf(__half2float(__ushort_as_half(sv.x)), dd, o[0]) + b.x;
    o[1] = fmaf(__half2float(__ushort_as_half(sv.y)), dd, o[1]) + b.y;
    o[2] = fmaf(__half2float(__ushort_as_half(sv.z)), dd, o[2]) + b.z;
    o[3] = fmaf(__half2float(__ushort_as_half(sv.w)), dd, o[3]) + b.w;
    if (relu) {
      o[0] = fmaxf(o[0], 0.f);
      o[1] = fmaxf(o[1], 0.f);
      o[2] = fmaxf(o[2], 0.f);
      o[3] = fmaxf(o[3], 0.f);
    }
    __half hh[4];
    hh[0] = __float2half_rn(o[0]);
    hh[1] = __float2half_rn(o[1]);
    hh[2] = __float2half_rn(o[2]);
    hh[3] = __float2half_rn(o[3]);
    *reinterpret_cast<uint2*>(&out[(size_t)node * FD + q * 4]) =
        *reinterpret_cast<uint2*>(hh);
  }
}

// Layer 3 fused: agg(h2) into LDS, then per-node 128x16 matmul with
// W3' (=W3@Wl) + b3' (=b3@Wl+bl) -> out[node][16]. One-shot grid.
__global__ __launch_bounds__(256) void k_agg_lin(const __half* __restrict__ t,
                                                 const int* __restrict__ ptr,
                                                 const int2* __restrict__ sn,
                                                 const float* __restrict__ dis,
                                                 const float* __restrict__ W3p,
                                                 const float* __restrict__ b3p,
                                                 float* __restrict__ out) {
  __shared__ float hl[4][FD];
  int wid = threadIdx.x >> 6;
  int lane = threadIdx.x & 63;
  int node = blockIdx.x * 4 + wid;
  float d = dis[node];
  float dd = d * d;
  float o[4];
  agg_wave(t, ptr, sn, node, lane, o);
  if (lane < 32) {
    int q = lane;
    ushort4 sv = *reinterpret_cast<const ushort4*>(&t[(size_t)node * FD + q * 4]);
    hl[wid][q * 4 + 0] = fmaf(__half2float(__ushort_as_half(sv.x)), dd, o[0]);
    hl[wid][q * 4 + 1] = fmaf(__half2float(__ushort_as_half(sv.y)), dd, o[1]);
    hl[wid][q * 4 + 2] = fmaf(__half2float(__ushort_as_half(sv.z)), dd, o[2]);
    hl[wid][q * 4 + 3] = fmaf(__half2float(__ushort_as_half(sv.w)), dd, o[3]);
  }
  __syncthreads();
  int c = lane & 15, kc = lane >> 4;
  float s = 0.f;
#pragma unroll
  for (int k0 = 0; k0 < 32; ++k0) {
    int k = kc * 32 + k0;
    s = fmaf(hl[wid][k], W3p[k * NCLS + c], s);
  }
  s += __shfl(s, lane ^ 16, 64);
  s += __shfl(s, lane ^ 32, 64);
  if (lane < NCLS)
    out[(size_t)node * NCLS + lane] = s + b3p[lane];
}

extern "C" void kernel_launch(void* const* d_in, const int* in_sizes, int n_in,
                              void* d_out, int out_size, void* d_ws, size_t ws_size,
                              hipStream_t stream) {
  const float* x  = (const float*)d_in[0];
  const int*   ei = (const int*)d_in[1];
  const float* W1 = (const float*)d_in[2];
  const float* b1 = (const float*)d_in[3];
  const float* W2 = (const float*)d_in[4];
  const float* b2 = (const float*)d_in[5];
  const float* W3 = (const float*)d_in[6];
  const float* b3 = (const float*)d_in[7];
  const float* Wl = (const float*)d_in[8];
  const float* bl = (const float*)d_in[9];
  float* out = (float*)d_out;

  const int n = in_sizes[0] / FD;      // 50000
  const int e = in_sizes[1] / 2;       // 600000
  const int* src = ei;                 // edge_index[0]
  const int* dst = ei + e;             // edge_index[1]

  // workspace carve
  __half* thA = (__half*)d_ws;                        // n*FD halves
  __half* thB = thA + (size_t)n * FD;                 // n*FD halves
  __half* wp1 = thB + (size_t)n * FD;                 // 16384 (W1 packed)
  __half* wp2 = wp1 + 16384;                          // 16384 (W2 packed)
  float*  W3p = (float*)(wp2 + 16384);                // 2048
  float*  b3p = W3p + 2048;                           // 16
  int*   degi = (int*)(b3p + 16);                     // n
  float* dis  = (float*)(degi + n);                   // n
  int*   ptr  = (int*)(dis + n);                      // n+1
  int*   cur  = ptr + n + 1;                          // n
  int*   bsum = cur + n;                              // <=64
  int2*  sn   = (int2*)(((uintptr_t)(bsum + 64) + 15) & ~(uintptr_t)15);  // e

  const int gn = (n + 255) / 256;
  const int ge = (e + 255) / 256;
  const int nb = (n + 1023) / 1024;

  hipMemsetAsync(degi, 0, (size_t)n * sizeof(int), stream);
  k_count<<<ge, 256, 0, stream>>>(dst, degi, e);
  k_scanA<<<nb, 1024, 0, stream>>>(degi, ptr, bsum, dis, n);
  k_scanB<<<1, 64, 0, stream>>>(bsum, nb);
  k_scanC<<<gn, 256, 0, stream>>>(ptr, cur, bsum, n, e);
  k_fill<<<ge, 256, 0, stream>>>(src, dst, cur, dis, sn, e);
  k_convW2<<<128, 256, 0, stream>>>(W1, W2, wp1);
  k_fuse3<<<1, 256, 0, stream>>>(W3, Wl, b3, bl, W3p, b3p);

  const int gG = (n + 63) / 64;  // 782 row-tiles
  const int ga = n / 4;          // 12500 blocks, 4 nodes (waves) each

  k_gemm_mfma<<<gG, 256, 0, stream>>>(x, 1, wp1, thA, n);
  k_agg<<<ga, 256, 0, stream>>>(thA, ptr, sn, dis, b1, thB, 1);
  k_gemm_mfma<<<gG, 256, 0, stream>>>(thB, 0, wp2, thA, n);
  k_agg<<<ga, 256, 0, stream>>>(thA, ptr, sn, dis, b2, thB, 1);
  k_agg_lin<<<ga, 256, 0, stream>>>(thB, ptr, sn, dis, W3p, b3p, out);
}